// Round 9
// baseline (504.717 us; speedup 1.0000x reference)
//
#include <hip/hip_runtime.h>
#include <stdint.h>

#define NN 50000
#define NE 600000
#define DIM 128
#define BN_EPS 1e-5f
#define NCHUNK ((NN + 255) / 256)   // 196 scan chunks

typedef __attribute__((ext_vector_type(8))) short bf16x8;
typedef __attribute__((ext_vector_type(4))) float f32x4;

__device__ __forceinline__ unsigned short f2b(float f) {
    unsigned u = __float_as_uint(f);
    u += 0x7FFF + ((u >> 16) & 1);          // RNE
    return (unsigned short)(u >> 16);
}
__device__ __forceinline__ float b2f(unsigned short h) {
    return __uint_as_float((unsigned)h << 16);
}

// ---------------- init: zero counts/stats + split W into bf16 hi/lo ----------------

__global__ __launch_bounds__(256) void init_k(int* __restrict__ counts,
                                              double* __restrict__ gsum,
                                              double* __restrict__ gsumsq,
                                              const float* __restrict__ w0,
                                              const float* __restrict__ w1,
                                              const float* __restrict__ w2,
                                              unsigned short* __restrict__ whi,
                                              unsigned short* __restrict__ wlo) {
    int bid = blockIdx.x;
    if (bid < NCHUNK) {
        int i = bid * 256 + threadIdx.x;
        if (i < NN) counts[i] = 0;
        if (i < DIM) { gsum[i] = 0.0; gsumsq[i] = 0.0; }
    } else {
        int i = (bid - NCHUNK) * 256 + threadIdx.x;   // [0, 3*4096)
        int which = i >> 12;
        int off = (i & 4095) * 4;
        const float* w = (which == 0) ? w0 : ((which == 1) ? w1 : w2);
        float4 v = *(const float4*)(w + off);
        ushort4 h = {f2b(v.x), f2b(v.y), f2b(v.z), f2b(v.w)};
        ushort4 l = {f2b(v.x - b2f(h.x)), f2b(v.y - b2f(h.y)),
                     f2b(v.z - b2f(h.z)), f2b(v.w - b2f(h.w))};
        *(ushort4*)(whi + (size_t)which * 16384 + off) = h;
        *(ushort4*)(wlo + (size_t)which * 16384 + off) = l;
    }
}

// ---------------- CSR build ----------------

__global__ void count_k(const int* __restrict__ dst, int* __restrict__ counts, int E) {
    int i = blockIdx.x * 256 + threadIdx.x;
    if (i < E) atomicAdd(&counts[dst[i]], 1);
}

__global__ __launch_bounds__(256) void chunksum_k(const int* __restrict__ counts,
                                                  int* __restrict__ bsum) {
    __shared__ int lds[256];
    int i = blockIdx.x * 256 + threadIdx.x;
    lds[threadIdx.x] = (i < NN) ? counts[i] : 0;
    __syncthreads();
    for (int off = 128; off > 0; off >>= 1) {
        if (threadIdx.x < (unsigned)off) lds[threadIdx.x] += lds[threadIdx.x + off];
        __syncthreads();
    }
    if (threadIdx.x == 0) bsum[blockIdx.x] = lds[0];
}

__global__ __launch_bounds__(256) void chunkscan_k(const int* __restrict__ bsum,
                                                   int* __restrict__ bbase,
                                                   int* __restrict__ offsets) {
    __shared__ int lds[256];
    int t = threadIdx.x;
    int v = (t < NCHUNK) ? bsum[t] : 0;
    lds[t] = v;
    __syncthreads();
    for (int off = 1; off < 256; off <<= 1) {
        int a = (t >= (unsigned)off) ? lds[t - off] : 0;
        __syncthreads();
        lds[t] += a;
        __syncthreads();
    }
    if (t < NCHUNK) bbase[t] = lds[t] - v;
    if (t == 0) offsets[NN] = NE;
}

__global__ __launch_bounds__(256) void scatteroff_k(const int* __restrict__ counts,
                                                    const int* __restrict__ bbase,
                                                    int* __restrict__ offsets,
                                                    int* __restrict__ cursor) {
    __shared__ int lds[256];
    int t = threadIdx.x;
    int i = blockIdx.x * 256 + t;
    int v = (i < NN) ? counts[i] : 0;
    lds[t] = v;
    __syncthreads();
    for (int off = 1; off < 256; off <<= 1) {
        int a = (t >= (unsigned)off) ? lds[t - off] : 0;
        __syncthreads();
        lds[t] += a;
        __syncthreads();
    }
    if (i < NN) {
        int excl = bbase[blockIdx.x] + lds[t] - v;
        offsets[i] = excl;
        cursor[i] = excl;
    }
}

// CSR fill + sequential-streaming eattr -> CSR-ordered bf16 copy.
template <bool WEBF>
__global__ __launch_bounds__(256) void fillcvt_k(
        const int* __restrict__ dst, const int* __restrict__ src,
        const float* __restrict__ eattr, int* __restrict__ cursor,
        int* __restrict__ csrc, int* __restrict__ eidx,
        unsigned short* __restrict__ ebf) {
    int lane = threadIdx.x & 31;
    int g = blockIdx.x * 8 + (threadIdx.x >> 5);
    int base = g * 32;
    if (base >= NE) return;                 // NE % 32 == 0: full groups only
    int i = base + lane;
    int d = dst[i];
    int p = atomicAdd(&cursor[d], 1);
    csrc[p] = src[i];
    if (!WEBF) { eidx[p] = i; return; }
    int f = lane * 4;
    for (int t = 0; t < 32; ++t) {
        int pt = __shfl(p, t, 32);
        float4 v = *(const float4*)(eattr + (size_t)(base + t) * DIM + f);
        ushort4 o = {f2b(v.x), f2b(v.y), f2b(v.z), f2b(v.w)};
        *(ushort4*)(ebf + (size_t)pt * DIM + f) = o;
    }
}

// ---------------- fused layer kernel ----------------
// Per block: 16 nodes, 4 waves. Aggregate: wave-per-node (4 nodes sequential
// per wave), 2 edges/iter (lane = eslot*32 + feature-lane), width-64 shfl
// index broadcast, halves combined via shfl_xor(32). No half-wave loop
// divergence. GEMM: bf16-A x split-bf16-W MFMA + BN stats (f64 atomics).
// XMODE: 0 = x fp32 identity (layer 1), 1 = x bf16 with scale/shift.
// EMODE: 0 = sequential bf16 ebf, 1 = fallback fp32 eattr via eidx.
template <int XMODE, int EMODE>
__global__ __launch_bounds__(256) void layer_k(
        const float* __restrict__ xf, const unsigned short* __restrict__ xb,
        const float* __restrict__ scale, const float* __restrict__ shift,
        const unsigned short* __restrict__ ebf, const float* __restrict__ eattr,
        const int* __restrict__ eidx, const int* __restrict__ offsets,
        const int* __restrict__ csrc,
        const unsigned short* __restrict__ whi, const unsigned short* __restrict__ wlo,
        const float* __restrict__ bias, unsigned short* __restrict__ yb,
        double* __restrict__ gsum, double* __restrict__ gsumsq) {
    __shared__ float sS[16][DIM + 4];        // stride 528B
    __shared__ unsigned short ylds[16][136];

    int tid = threadIdx.x;
    int lane = tid & 63;
    int wv = tid >> 6;        // wave id 0..3
    int eslot = lane >> 5;    // which of 2 concurrent edges
    int fl = lane & 31;       // feature lane
    int n0 = blockIdx.x * 16;
    int f = fl * 4;

    float4 sc, sh;
    if (XMODE) {
        sc = *(const float4*)(scale + f);
        sh = *(const float4*)(shift + f);
    }

    for (int j = 0; j < 4; ++j) {
        int n = n0 + wv * 4 + j;
        float4 acc = make_float4(0.f, 0.f, 0.f, 0.f);
        int beg = offsets[n], end = offsets[n + 1];
        for (int b = beg; b < end; b += 64) {
            int kk = b + lane;
            int s_l = (kk < end) ? csrc[kk] : 0;
            int e_l = 0;
            if (EMODE == 1) e_l = (kk < end) ? eidx[kk] : 0;
            int m = end - b;
            if (m > 64) m = 64;
            int titer = (m + 1) >> 1;
#pragma unroll 4
            for (int t = 0; t < titer; ++t) {
                int idx = 2 * t + eslot;
                if (idx < m) {
                    int s = __shfl(s_l, idx);     // width 64
                    float4 ev;
                    if (EMODE == 0) {
                        ushort4 eb = *(const ushort4*)(ebf + (size_t)(b + idx) * DIM + f);
                        ev = make_float4(b2f(eb.x), b2f(eb.y), b2f(eb.z), b2f(eb.w));
                    } else {
                        int e = __shfl(e_l, idx);
                        ev = *(const float4*)(eattr + (size_t)e * DIM + f);
                    }
                    float4 xv;
                    if (XMODE == 0) {
                        xv = *(const float4*)(xf + (size_t)s * DIM + f);
                    } else {
                        ushort4 u = *(const ushort4*)(xb + (size_t)s * DIM + f);
                        xv = make_float4(fmaf(b2f(u.x), sc.x, sh.x),
                                         fmaf(b2f(u.y), sc.y, sh.y),
                                         fmaf(b2f(u.z), sc.z, sh.z),
                                         fmaf(b2f(u.w), sc.w, sh.w));
                    }
                    acc.x += fmaxf(xv.x + ev.x, 0.f);
                    acc.y += fmaxf(xv.y + ev.y, 0.f);
                    acc.z += fmaxf(xv.z + ev.z, 0.f);
                    acc.w += fmaxf(xv.w + ev.w, 0.f);
                }
            }
        }
        // combine the two edge-slot halves (lane i <-> lane i^32, same feature)
        acc.x += __shfl_xor(acc.x, 32);
        acc.y += __shfl_xor(acc.y, 32);
        acc.z += __shfl_xor(acc.z, 32);
        acc.w += __shfl_xor(acc.w, 32);
        if (eslot == 0) {
            float4 xn;
            if (XMODE == 0) {
                xn = *(const float4*)(xf + (size_t)n * DIM + f);
            } else {
                ushort4 u = *(const ushort4*)(xb + (size_t)n * DIM + f);
                xn = make_float4(fmaf(b2f(u.x), sc.x, sh.x), fmaf(b2f(u.y), sc.y, sh.y),
                                 fmaf(b2f(u.z), sc.z, sh.z), fmaf(b2f(u.w), sc.w, sh.w));
            }
            float4 o = make_float4(xn.x + acc.x, xn.y + acc.y,
                                   xn.z + acc.z, xn.w + acc.w);
            *(float4*)(&sS[wv * 4 + j][f]) = o;
        }
    }
    __syncthreads();

    // ---- GEMM phase: A (bf16) x [Whi + Wlo] ----
    int row = lane & 15;      // A row (node) / B col (dim)
    int kg = lane >> 4;       // k-group
    int d0 = wv * 32;
    const unsigned short* bh = whi + (size_t)(d0 + row) * DIM + kg * 8;
    const unsigned short* bl = wlo + (size_t)(d0 + row) * DIM + kg * 8;

    f32x4 acc0 = {0.f, 0.f, 0.f, 0.f};
    f32x4 acc1 = {0.f, 0.f, 0.f, 0.f};
#pragma unroll
    for (int ks = 0; ks < 4; ++ks) {
        const float* ap = &sS[row][kg * 8 + ks * 32];
        bf16x8 a;
#pragma unroll
        for (int j = 0; j < 8; ++j) a[j] = (short)f2b(ap[j]);
        bf16x8 b0h = *(const bf16x8*)(bh + ks * 32);
        bf16x8 b0l = *(const bf16x8*)(bl + ks * 32);
        bf16x8 b1h = *(const bf16x8*)(bh + 16 * DIM + ks * 32);
        bf16x8 b1l = *(const bf16x8*)(bl + 16 * DIM + ks * 32);
        acc0 = __builtin_amdgcn_mfma_f32_16x16x32_bf16(a, b0h, acc0, 0, 0, 0);
        acc0 = __builtin_amdgcn_mfma_f32_16x16x32_bf16(a, b0l, acc0, 0, 0, 0);
        acc1 = __builtin_amdgcn_mfma_f32_16x16x32_bf16(a, b1h, acc1, 0, 0, 0);
        acc1 = __builtin_amdgcn_mfma_f32_16x16x32_bf16(a, b1l, acc1, 0, 0, 0);
    }

    float bias0 = bias[d0 + row];
    float bias1 = bias[d0 + 16 + row];
    float s0 = 0.f, q0 = 0.f, s1 = 0.f, q1 = 0.f;
#pragma unroll
    for (int r = 0; r < 4; ++r) {
        int m = kg * 4 + r;
        float y0 = fmaxf(acc0[r] + bias0, 0.f);
        float y1 = fmaxf(acc1[r] + bias1, 0.f);
        ylds[m][d0 + row] = f2b(y0);
        ylds[m][d0 + 16 + row] = f2b(y1);
        s0 += y0; q0 += y0 * y0;
        s1 += y1; q1 += y1 * y1;
    }
    s0 += __shfl_xor(s0, 16); s0 += __shfl_xor(s0, 32);
    q0 += __shfl_xor(q0, 16); q0 += __shfl_xor(q0, 32);
    s1 += __shfl_xor(s1, 16); s1 += __shfl_xor(s1, 32);
    q1 += __shfl_xor(q1, 16); q1 += __shfl_xor(q1, 32);
    if (kg == 0) {
        atomicAdd(&gsum[d0 + row], (double)s0);
        atomicAdd(&gsumsq[d0 + row], (double)q0);
        atomicAdd(&gsum[d0 + 16 + row], (double)s1);
        atomicAdd(&gsumsq[d0 + 16 + row], (double)q1);
    }
    __syncthreads();
    int nrow = tid >> 4, seg = tid & 15;
    *(float4*)(yb + (size_t)(n0 + nrow) * DIM + seg * 8) =
        *(const float4*)(&ylds[nrow][seg * 8]);
}

// derive BN scale/shift; zero stats for next layer
__global__ void finalize_k(double* __restrict__ gsum, double* __restrict__ gsumsq,
                           const float* __restrict__ gamma, const float* __restrict__ beta,
                           float* __restrict__ scale, float* __restrict__ shift) {
    int d = threadIdx.x;
    if (d < DIM) {
        double mean = gsum[d] * (1.0 / NN);
        double var = gsumsq[d] * (1.0 / NN) - mean * mean;
        float sc = gamma[d] * rsqrtf((float)var + BN_EPS);
        scale[d] = sc;
        shift[d] = beta[d] - (float)mean * sc;
        gsum[d] = 0.0;
        gsumsq[d] = 0.0;
    }
}

__global__ __launch_bounds__(256) void norm_out_k(
        const unsigned short* __restrict__ yb, const float* __restrict__ scale,
        const float* __restrict__ shift, float* __restrict__ out) {
    int i = blockIdx.x * 256 + threadIdx.x;   // [0, NN*DIM/4)
    int f = (i & 31) * 4;
    ushort4 y = *(const ushort4*)(yb + (size_t)i * 4);
    float4 sc = *(const float4*)(scale + f);
    float4 sh = *(const float4*)(shift + f);
    float4 o;
    o.x = fmaf(b2f(y.x), sc.x, sh.x);
    o.y = fmaf(b2f(y.y), sc.y, sh.y);
    o.z = fmaf(b2f(y.z), sc.z, sh.z);
    o.w = fmaf(b2f(y.w), sc.w, sh.w);
    ((float4*)out)[i] = o;
}

// ---------------- launch ----------------

extern "C" void kernel_launch(void* const* d_in, const int* in_sizes, int n_in,
                              void* d_out, int out_size, void* d_ws, size_t ws_size,
                              hipStream_t stream) {
    const int* edge_index = (const int*)d_in[0];
    const int* srcs = edge_index;
    const int* dsts = edge_index + NE;
    const float* node_attr = (const float*)d_in[1];
    const float* eattr = (const float*)d_in[2];
    const float* Wp[3]    = {(const float*)d_in[3],  (const float*)d_in[7],  (const float*)d_in[11]};
    const float* bp[3]    = {(const float*)d_in[4],  (const float*)d_in[8],  (const float*)d_in[12]};
    const float* gammap[3]= {(const float*)d_in[5],  (const float*)d_in[9],  (const float*)d_in[13]};
    const float* betap[3] = {(const float*)d_in[6],  (const float*)d_in[10], (const float*)d_in[14]};

    size_t off = 0;
    char* base = (char*)d_ws;
    auto carve = [&](size_t bytes) -> void* {
        void* p = base + off;
        off += (bytes + 255) & ~(size_t)255;
        return p;
    };
    unsigned short* ybufA = (unsigned short*)carve((size_t)NN * DIM * 2);
    unsigned short* ybufB = (unsigned short*)carve((size_t)NN * DIM * 2);
    int* csrc    = (int*)carve((size_t)NE * 4);
    int* eidx    = (int*)carve((size_t)NE * 4);
    int* offsets = (int*)carve((size_t)(NN + 1) * 4);
    int* cursor  = (int*)carve((size_t)NN * 4);
    int* bsum    = (int*)carve((size_t)NCHUNK * 4);
    int* bbase   = (int*)carve((size_t)NCHUNK * 4);
    int* counts  = (int*)carve((size_t)NN * 4);
    double* gsum = (double*)carve(DIM * 8);
    double* gsumsq = (double*)carve(DIM * 8);
    float* scb   = (float*)carve(3 * DIM * 4);
    float* shb   = (float*)carve(3 * DIM * 4);
    unsigned short* whi = (unsigned short*)carve(3 * DIM * DIM * 2);
    unsigned short* wlo = (unsigned short*)carve(3 * DIM * DIM * 2);
    int use_ebf = (off + (size_t)NE * DIM * 2 <= ws_size);
    unsigned short* ebf = use_ebf ? (unsigned short*)carve((size_t)NE * DIM * 2) : nullptr;

    init_k<<<NCHUNK + 48, 256, 0, stream>>>(counts, gsum, gsumsq,
                                            Wp[0], Wp[1], Wp[2], whi, wlo);
    count_k<<<(NE + 255) / 256, 256, 0, stream>>>(dsts, counts, NE);
    chunksum_k<<<NCHUNK, 256, 0, stream>>>(counts, bsum);
    chunkscan_k<<<1, 256, 0, stream>>>(bsum, bbase, offsets);
    scatteroff_k<<<NCHUNK, 256, 0, stream>>>(counts, bbase, offsets, cursor);
    if (use_ebf)
        fillcvt_k<true><<<(NE / 32 + 7) / 8, 256, 0, stream>>>(dsts, srcs, eattr, cursor,
                                                               csrc, eidx, ebf);
    else
        fillcvt_k<false><<<(NE / 32 + 7) / 8, 256, 0, stream>>>(dsts, srcs, eattr, cursor,
                                                                csrc, eidx, nullptr);

    // ---- layer 1: node_attr -> ybufA ----
    if (use_ebf)
        layer_k<0, 0><<<NN / 16, 256, 0, stream>>>(node_attr, nullptr, nullptr, nullptr,
                                                   ebf, eattr, eidx, offsets, csrc,
                                                   whi, wlo, bp[0], ybufA, gsum, gsumsq);
    else
        layer_k<0, 1><<<NN / 16, 256, 0, stream>>>(node_attr, nullptr, nullptr, nullptr,
                                                   nullptr, eattr, eidx, offsets, csrc,
                                                   whi, wlo, bp[0], ybufA, gsum, gsumsq);
    finalize_k<<<1, DIM, 0, stream>>>(gsum, gsumsq, gammap[0], betap[0], scb, shb);

    // ---- layers 2,3: ping-pong A->B->A ----
    unsigned short* xin = ybufA;
    unsigned short* yout = ybufB;
    for (int l = 1; l < 3; ++l) {
        const float* sc = scb + (l - 1) * DIM;
        const float* sh = shb + (l - 1) * DIM;
        if (use_ebf)
            layer_k<1, 0><<<NN / 16, 256, 0, stream>>>(nullptr, xin, sc, sh,
                                                       ebf, eattr, eidx, offsets, csrc,
                                                       whi + l * DIM * DIM, wlo + l * DIM * DIM,
                                                       bp[l], yout, gsum, gsumsq);
        else
            layer_k<1, 1><<<NN / 16, 256, 0, stream>>>(nullptr, xin, sc, sh,
                                                       nullptr, eattr, eidx, offsets, csrc,
                                                       whi + l * DIM * DIM, wlo + l * DIM * DIM,
                                                       bp[l], yout, gsum, gsumsq);
        finalize_k<<<1, DIM, 0, stream>>>(gsum, gsumsq, gammap[l], betap[l],
                                          scb + l * DIM, shb + l * DIM);
        unsigned short* t = xin; xin = yout; yout = t;
    }
    norm_out_k<<<NN * DIM / 4 / 256, 256, 0, stream>>>(xin, scb + 2 * DIM, shb + 2 * DIM,
                                                       (float*)d_out);
}

// Round 10
// 491.871 us; speedup vs baseline: 1.0261x; 1.0261x over previous
//
#include <hip/hip_runtime.h>
#include <stdint.h>

#define NN 50000
#define NE 600000
#define DIM 128
#define BN_EPS 1e-5f
#define NCHUNK ((NN + 255) / 256)   // 196 scan chunks
#define NABBLK (NN * DIM / 4 / 256) // 6250 node_attr-convert blocks

typedef __attribute__((ext_vector_type(8))) short bf16x8;
typedef __attribute__((ext_vector_type(4))) float f32x4;
typedef __attribute__((ext_vector_type(2))) unsigned int u32x2;

__device__ __forceinline__ unsigned short f2b(float f) {
    unsigned u = __float_as_uint(f);
    u += 0x7FFF + ((u >> 16) & 1);          // RNE
    return (unsigned short)(u >> 16);
}
__device__ __forceinline__ float b2f(unsigned short h) {
    return __uint_as_float((unsigned)h << 16);
}

// ---------------- init: zero counts/stats, split W, convert node_attr ----------------

__global__ __launch_bounds__(256) void init_k(int* __restrict__ counts,
                                              double* __restrict__ gsum,
                                              double* __restrict__ gsumsq,
                                              const float* __restrict__ w0,
                                              const float* __restrict__ w1,
                                              const float* __restrict__ w2,
                                              unsigned short* __restrict__ whi,
                                              unsigned short* __restrict__ wlo,
                                              const float* __restrict__ xf,
                                              unsigned short* __restrict__ nabf) {
    int bid = blockIdx.x;
    if (bid < NCHUNK) {
        int i = bid * 256 + threadIdx.x;
        if (i < NN) counts[i] = 0;
        if (i < 3 * DIM) { gsum[i] = 0.0; gsumsq[i] = 0.0; }
    } else if (bid < NCHUNK + 48) {
        int i = (bid - NCHUNK) * 256 + threadIdx.x;   // [0, 3*4096)
        int which = i >> 12;
        int off = (i & 4095) * 4;
        const float* w = (which == 0) ? w0 : ((which == 1) ? w1 : w2);
        float4 v = *(const float4*)(w + off);
        ushort4 h = {f2b(v.x), f2b(v.y), f2b(v.z), f2b(v.w)};
        ushort4 l = {f2b(v.x - b2f(h.x)), f2b(v.y - b2f(h.y)),
                     f2b(v.z - b2f(h.z)), f2b(v.w - b2f(h.w))};
        *(ushort4*)(whi + (size_t)which * 16384 + off) = h;
        *(ushort4*)(wlo + (size_t)which * 16384 + off) = l;
    } else {
        int idx = (bid - NCHUNK - 48) * 256 + threadIdx.x;  // [0, NN*DIM/4)
        f32x4 v = __builtin_nontemporal_load((const f32x4*)(xf + (size_t)idx * 4));
        u32x2 o;
        o[0] = (unsigned)f2b(v[0]) | ((unsigned)f2b(v[1]) << 16);
        o[1] = (unsigned)f2b(v[2]) | ((unsigned)f2b(v[3]) << 16);
        __builtin_nontemporal_store(o, (u32x2*)(nabf + (size_t)idx * 4));
    }
}

// ---------------- CSR build ----------------

__global__ void count_k(const int* __restrict__ dst, int* __restrict__ counts, int E) {
    int i = blockIdx.x * 256 + threadIdx.x;
    if (i < E) atomicAdd(&counts[dst[i]], 1);
}

__global__ __launch_bounds__(256) void chunksum_k(const int* __restrict__ counts,
                                                  int* __restrict__ bsum) {
    __shared__ int lds[256];
    int i = blockIdx.x * 256 + threadIdx.x;
    lds[threadIdx.x] = (i < NN) ? counts[i] : 0;
    __syncthreads();
    for (int off = 128; off > 0; off >>= 1) {
        if (threadIdx.x < (unsigned)off) lds[threadIdx.x] += lds[threadIdx.x + off];
        __syncthreads();
    }
    if (threadIdx.x == 0) bsum[blockIdx.x] = lds[0];
}

__global__ __launch_bounds__(256) void chunkscan_k(const int* __restrict__ bsum,
                                                   int* __restrict__ bbase,
                                                   int* __restrict__ offsets) {
    __shared__ int lds[256];
    int t = threadIdx.x;
    int v = (t < NCHUNK) ? bsum[t] : 0;
    lds[t] = v;
    __syncthreads();
    for (int off = 1; off < 256; off <<= 1) {
        int a = (t >= (unsigned)off) ? lds[t - off] : 0;
        __syncthreads();
        lds[t] += a;
        __syncthreads();
    }
    if (t < NCHUNK) bbase[t] = lds[t] - v;
    if (t == 0) offsets[NN] = NE;
}

__global__ __launch_bounds__(256) void scatteroff_k(const int* __restrict__ counts,
                                                    const int* __restrict__ bbase,
                                                    int* __restrict__ offsets,
                                                    int* __restrict__ cursor) {
    __shared__ int lds[256];
    int t = threadIdx.x;
    int i = blockIdx.x * 256 + t;
    int v = (i < NN) ? counts[i] : 0;
    lds[t] = v;
    __syncthreads();
    for (int off = 1; off < 256; off <<= 1) {
        int a = (t >= (unsigned)off) ? lds[t - off] : 0;
        __syncthreads();
        lds[t] += a;
        __syncthreads();
    }
    if (i < NN) {
        int excl = bbase[blockIdx.x] + lds[t] - v;
        offsets[i] = excl;
        cursor[i] = excl;
    }
}

// CSR fill + sequential-streaming eattr -> CSR-ordered bf16 copy (NT in/out).
template <bool WEBF>
__global__ __launch_bounds__(256) void fillcvt_k(
        const int* __restrict__ dst, const int* __restrict__ src,
        const float* __restrict__ eattr, int* __restrict__ cursor,
        int* __restrict__ csrc, int* __restrict__ eidx,
        unsigned short* __restrict__ ebf) {
    int lane = threadIdx.x & 31;
    int g = blockIdx.x * 8 + (threadIdx.x >> 5);
    int base = g * 32;
    if (base >= NE) return;                 // NE % 32 == 0: full groups only
    int i = base + lane;
    int d = dst[i];
    int p = atomicAdd(&cursor[d], 1);
    csrc[p] = src[i];
    if (!WEBF) { eidx[p] = i; return; }
    int f = lane * 4;
#pragma unroll 4
    for (int t = 0; t < 32; ++t) {
        int pt = __shfl(p, t, 32);
        f32x4 v = __builtin_nontemporal_load(
            (const f32x4*)(eattr + (size_t)(base + t) * DIM + f));
        u32x2 o;
        o[0] = (unsigned)f2b(v[0]) | ((unsigned)f2b(v[1]) << 16);
        o[1] = (unsigned)f2b(v[2]) | ((unsigned)f2b(v[3]) << 16);
        __builtin_nontemporal_store(o, (u32x2*)(ebf + (size_t)pt * DIM + f));
    }
}

// ---------------- fused layer kernel ----------------
// Per block: 16 nodes. Phase A: 8 groups x 32 lanes aggregate (2 nodes each)
// into fp32 LDS. Phase B: bf16-A x split-bf16-W MFMA GEMM; per-layer BN stats
// accumulated via f64 atomics into gs_cur. BN of the PREVIOUS layer is folded
// on the fly: scale/shift computed per-thread from gs_prev (XMODE==1).
// XMODE: 1 = x bf16 + BN-fold from prev stats, 2 = x bf16 identity (layer 1).
// EMODE: 0 = sequential bf16 ebf (NT), 1 = fallback fp32 eattr via eidx.
template <int XMODE, int EMODE>
__global__ __launch_bounds__(256) void layer_k(
        const unsigned short* __restrict__ xb,
        const double* __restrict__ gs_prev, const double* __restrict__ gq_prev,
        const float* __restrict__ gamma_prev, const float* __restrict__ beta_prev,
        const unsigned short* __restrict__ ebf, const float* __restrict__ eattr,
        const int* __restrict__ eidx, const int* __restrict__ offsets,
        const int* __restrict__ csrc,
        const unsigned short* __restrict__ whi, const unsigned short* __restrict__ wlo,
        const float* __restrict__ bias, unsigned short* __restrict__ yb,
        double* __restrict__ gs_cur, double* __restrict__ gq_cur) {
    __shared__ float sS[16][DIM + 4];        // stride 528B
    __shared__ unsigned short ylds[16][136];

    int tid = threadIdx.x;
    int lane31 = tid & 31;
    int grp = tid >> 5;
    int n0 = blockIdx.x * 16;
    int f = lane31 * 4;

    f32x4 sc, sh;
    if (XMODE == 1) {
#pragma unroll
        for (int j = 0; j < 4; ++j) {
            int d = f + j;
            double mean = gs_prev[d] * (1.0 / NN);
            double var = gq_prev[d] * (1.0 / NN) - mean * mean;
            float s = gamma_prev[d] * rsqrtf((float)var + BN_EPS);
            sc[j] = s;
            sh[j] = beta_prev[d] - (float)mean * s;
        }
    }

#pragma unroll
    for (int sub = 0; sub < 2; ++sub) {
        int n = n0 + grp * 2 + sub;
        float4 acc = make_float4(0.f, 0.f, 0.f, 0.f);
        int beg = offsets[n], end = offsets[n + 1];
        for (int b = beg; b < end; b += 32) {
            int kk = b + lane31;
            int s_l = (kk < end) ? csrc[kk] : 0;
            int e_l = 0;
            if (EMODE == 1) e_l = (kk < end) ? eidx[kk] : 0;
            int cnt = end - b;
            if (cnt > 32) cnt = 32;
#pragma unroll 4
            for (int t = 0; t < cnt; ++t) {
                int s = __shfl(s_l, t, 32);
                float4 ev;
                if (EMODE == 0) {
                    u32x2 ew = __builtin_nontemporal_load(
                        (const u32x2*)(ebf + (size_t)(b + t) * DIM + f));
                    ev = make_float4(b2f((unsigned short)(ew[0] & 0xFFFFu)),
                                     b2f((unsigned short)(ew[0] >> 16)),
                                     b2f((unsigned short)(ew[1] & 0xFFFFu)),
                                     b2f((unsigned short)(ew[1] >> 16)));
                } else {
                    int e = __shfl(e_l, t, 32);
                    ev = *(const float4*)(eattr + (size_t)e * DIM + f);
                }
                ushort4 u = *(const ushort4*)(xb + (size_t)s * DIM + f);
                float4 xv;
                if (XMODE == 1) {
                    xv = make_float4(fmaf(b2f(u.x), sc[0], sh[0]),
                                     fmaf(b2f(u.y), sc[1], sh[1]),
                                     fmaf(b2f(u.z), sc[2], sh[2]),
                                     fmaf(b2f(u.w), sc[3], sh[3]));
                } else {
                    xv = make_float4(b2f(u.x), b2f(u.y), b2f(u.z), b2f(u.w));
                }
                acc.x += fmaxf(xv.x + ev.x, 0.f);
                acc.y += fmaxf(xv.y + ev.y, 0.f);
                acc.z += fmaxf(xv.z + ev.z, 0.f);
                acc.w += fmaxf(xv.w + ev.w, 0.f);
            }
        }
        ushort4 u = *(const ushort4*)(xb + (size_t)n * DIM + f);
        float4 xn;
        if (XMODE == 1) {
            xn = make_float4(fmaf(b2f(u.x), sc[0], sh[0]), fmaf(b2f(u.y), sc[1], sh[1]),
                             fmaf(b2f(u.z), sc[2], sh[2]), fmaf(b2f(u.w), sc[3], sh[3]));
        } else {
            xn = make_float4(b2f(u.x), b2f(u.y), b2f(u.z), b2f(u.w));
        }
        float4 o = make_float4(xn.x + acc.x, xn.y + acc.y, xn.z + acc.z, xn.w + acc.w);
        *(float4*)(&sS[grp * 2 + sub][f]) = o;
    }
    __syncthreads();

    // ---- GEMM phase: A (bf16) x [Whi + Wlo] ----
    int wv = tid >> 6;
    int lane = tid & 63;
    int row = lane & 15;      // A row (node) / B col (dim)
    int kg = lane >> 4;       // k-group
    int d0 = wv * 32;
    const unsigned short* bh = whi + (size_t)(d0 + row) * DIM + kg * 8;
    const unsigned short* bl = wlo + (size_t)(d0 + row) * DIM + kg * 8;

    f32x4 acc0 = {0.f, 0.f, 0.f, 0.f};
    f32x4 acc1 = {0.f, 0.f, 0.f, 0.f};
#pragma unroll
    for (int ks = 0; ks < 4; ++ks) {
        const float* ap = &sS[row][kg * 8 + ks * 32];
        bf16x8 a;
#pragma unroll
        for (int j = 0; j < 8; ++j) a[j] = (short)f2b(ap[j]);
        bf16x8 b0h = *(const bf16x8*)(bh + ks * 32);
        bf16x8 b0l = *(const bf16x8*)(bl + ks * 32);
        bf16x8 b1h = *(const bf16x8*)(bh + 16 * DIM + ks * 32);
        bf16x8 b1l = *(const bf16x8*)(bl + 16 * DIM + ks * 32);
        acc0 = __builtin_amdgcn_mfma_f32_16x16x32_bf16(a, b0h, acc0, 0, 0, 0);
        acc0 = __builtin_amdgcn_mfma_f32_16x16x32_bf16(a, b0l, acc0, 0, 0, 0);
        acc1 = __builtin_amdgcn_mfma_f32_16x16x32_bf16(a, b1h, acc1, 0, 0, 0);
        acc1 = __builtin_amdgcn_mfma_f32_16x16x32_bf16(a, b1l, acc1, 0, 0, 0);
    }

    float bias0 = bias[d0 + row];
    float bias1 = bias[d0 + 16 + row];
    float s0 = 0.f, q0 = 0.f, s1 = 0.f, q1 = 0.f;
#pragma unroll
    for (int r = 0; r < 4; ++r) {
        int m = kg * 4 + r;
        float y0 = fmaxf(acc0[r] + bias0, 0.f);
        float y1 = fmaxf(acc1[r] + bias1, 0.f);
        ylds[m][d0 + row] = f2b(y0);
        ylds[m][d0 + 16 + row] = f2b(y1);
        s0 += y0; q0 += y0 * y0;
        s1 += y1; q1 += y1 * y1;
    }
    s0 += __shfl_xor(s0, 16); s0 += __shfl_xor(s0, 32);
    q0 += __shfl_xor(q0, 16); q0 += __shfl_xor(q0, 32);
    s1 += __shfl_xor(s1, 16); s1 += __shfl_xor(s1, 32);
    q1 += __shfl_xor(q1, 16); q1 += __shfl_xor(q1, 32);
    if (kg == 0) {
        atomicAdd(&gs_cur[d0 + row], (double)s0);
        atomicAdd(&gq_cur[d0 + row], (double)q0);
        atomicAdd(&gs_cur[d0 + 16 + row], (double)s1);
        atomicAdd(&gq_cur[d0 + 16 + row], (double)q1);
    }
    __syncthreads();
    int nrow = tid >> 4, seg = tid & 15;
    *(float4*)(yb + (size_t)(n0 + nrow) * DIM + seg * 8) =
        *(const float4*)(&ylds[nrow][seg * 8]);
}

// final BN applied from layer-3 stats, computed per-thread
__global__ __launch_bounds__(256) void norm_out_k(
        const unsigned short* __restrict__ yb,
        const double* __restrict__ gs, const double* __restrict__ gq,
        const float* __restrict__ gamma, const float* __restrict__ beta,
        float* __restrict__ out) {
    int i = blockIdx.x * 256 + threadIdx.x;   // [0, NN*DIM/4)
    int f = (i & 31) * 4;
    float sc[4], sh[4];
#pragma unroll
    for (int j = 0; j < 4; ++j) {
        int d = f + j;
        double mean = gs[d] * (1.0 / NN);
        double var = gq[d] * (1.0 / NN) - mean * mean;
        float s = gamma[d] * rsqrtf((float)var + BN_EPS);
        sc[j] = s;
        sh[j] = beta[d] - (float)mean * s;
    }
    ushort4 y = *(const ushort4*)(yb + (size_t)i * 4);
    float4 o;
    o.x = fmaf(b2f(y.x), sc[0], sh[0]);
    o.y = fmaf(b2f(y.y), sc[1], sh[1]);
    o.z = fmaf(b2f(y.z), sc[2], sh[2]);
    o.w = fmaf(b2f(y.w), sc[3], sh[3]);
    ((float4*)out)[i] = o;
}

// ---------------- launch ----------------

extern "C" void kernel_launch(void* const* d_in, const int* in_sizes, int n_in,
                              void* d_out, int out_size, void* d_ws, size_t ws_size,
                              hipStream_t stream) {
    const int* edge_index = (const int*)d_in[0];
    const int* srcs = edge_index;
    const int* dsts = edge_index + NE;
    const float* node_attr = (const float*)d_in[1];
    const float* eattr = (const float*)d_in[2];
    const float* Wp[3]    = {(const float*)d_in[3],  (const float*)d_in[7],  (const float*)d_in[11]};
    const float* bp[3]    = {(const float*)d_in[4],  (const float*)d_in[8],  (const float*)d_in[12]};
    const float* gammap[3]= {(const float*)d_in[5],  (const float*)d_in[9],  (const float*)d_in[13]};
    const float* betap[3] = {(const float*)d_in[6],  (const float*)d_in[10], (const float*)d_in[14]};

    size_t off = 0;
    char* base = (char*)d_ws;
    auto carve = [&](size_t bytes) -> void* {
        void* p = base + off;
        off += (bytes + 255) & ~(size_t)255;
        return p;
    };
    unsigned short* ybufA = (unsigned short*)carve((size_t)NN * DIM * 2);
    unsigned short* ybufB = (unsigned short*)carve((size_t)NN * DIM * 2);
    unsigned short* nabf = (unsigned short*)carve((size_t)NN * DIM * 2);
    int* csrc    = (int*)carve((size_t)NE * 4);
    int* eidx    = (int*)carve((size_t)NE * 4);
    int* offsets = (int*)carve((size_t)(NN + 1) * 4);
    int* cursor  = (int*)carve((size_t)NN * 4);
    int* bsum    = (int*)carve((size_t)NCHUNK * 4);
    int* bbase   = (int*)carve((size_t)NCHUNK * 4);
    int* counts  = (int*)carve((size_t)NN * 4);
    double* gsum = (double*)carve(3 * DIM * 8);    // per-layer stat sums
    double* gsumsq = (double*)carve(3 * DIM * 8);
    unsigned short* whi = (unsigned short*)carve(3 * DIM * DIM * 2);
    unsigned short* wlo = (unsigned short*)carve(3 * DIM * DIM * 2);
    int use_ebf = (off + (size_t)NE * DIM * 2 <= ws_size);
    unsigned short* ebf = use_ebf ? (unsigned short*)carve((size_t)NE * DIM * 2) : nullptr;

    init_k<<<NCHUNK + 48 + NABBLK, 256, 0, stream>>>(counts, gsum, gsumsq,
                                                     Wp[0], Wp[1], Wp[2], whi, wlo,
                                                     node_attr, nabf);
    count_k<<<(NE + 255) / 256, 256, 0, stream>>>(dsts, counts, NE);
    chunksum_k<<<NCHUNK, 256, 0, stream>>>(counts, bsum);
    chunkscan_k<<<1, 256, 0, stream>>>(bsum, bbase, offsets);
    scatteroff_k<<<NCHUNK, 256, 0, stream>>>(counts, bbase, offsets, cursor);
    if (use_ebf)
        fillcvt_k<true><<<(NE / 32 + 7) / 8, 256, 0, stream>>>(dsts, srcs, eattr, cursor,
                                                               csrc, eidx, ebf);
    else
        fillcvt_k<false><<<(NE / 32 + 7) / 8, 256, 0, stream>>>(dsts, srcs, eattr, cursor,
                                                                csrc, eidx, nullptr);

    // ---- layer 1: nabf (identity) -> ybufA, stats into gsum[0] ----
    if (use_ebf)
        layer_k<2, 0><<<NN / 16, 256, 0, stream>>>(nabf, nullptr, nullptr, nullptr, nullptr,
                                                   ebf, eattr, eidx, offsets, csrc,
                                                   whi, wlo, bp[0], ybufA, gsum, gsumsq);
    else
        layer_k<2, 1><<<NN / 16, 256, 0, stream>>>(nabf, nullptr, nullptr, nullptr, nullptr,
                                                   nullptr, eattr, eidx, offsets, csrc,
                                                   whi, wlo, bp[0], ybufA, gsum, gsumsq);

    // ---- layers 2,3: ping-pong A->B->A; BN of prev layer folded inline ----
    unsigned short* xin = ybufA;
    unsigned short* yout = ybufB;
    for (int l = 1; l < 3; ++l) {
        const double* gsp = gsum + (l - 1) * DIM;
        const double* gqp = gsumsq + (l - 1) * DIM;
        if (use_ebf)
            layer_k<1, 0><<<NN / 16, 256, 0, stream>>>(xin, gsp, gqp,
                                                       gammap[l - 1], betap[l - 1],
                                                       ebf, eattr, eidx, offsets, csrc,
                                                       whi + l * DIM * DIM, wlo + l * DIM * DIM,
                                                       bp[l], yout,
                                                       gsum + l * DIM, gsumsq + l * DIM);
        else
            layer_k<1, 1><<<NN / 16, 256, 0, stream>>>(xin, gsp, gqp,
                                                       gammap[l - 1], betap[l - 1],
                                                       nullptr, eattr, eidx, offsets, csrc,
                                                       whi + l * DIM * DIM, wlo + l * DIM * DIM,
                                                       bp[l], yout,
                                                       gsum + l * DIM, gsumsq + l * DIM);
        unsigned short* t = xin; xin = yout; yout = t;
    }
    norm_out_k<<<NN * DIM / 4 / 256, 256, 0, stream>>>(xin, gsum + 2 * DIM, gsumsq + 2 * DIM,
                                                       gammap[2], betap[2], (float*)d_out);
}

// Round 11
// 466.030 us; speedup vs baseline: 1.0830x; 1.0554x over previous
//
#include <hip/hip_runtime.h>
#include <stdint.h>

#define NN 50000
#define NE 600000
#define DIM 128
#define BN_EPS 1e-5f
#define NCHUNK ((NN + 255) / 256)   // 196 scan chunks
#define NABBLK (NN * DIM / 4 / 256) // 6250 node_attr-convert blocks

typedef __attribute__((ext_vector_type(8))) short bf16x8;
typedef __attribute__((ext_vector_type(4))) float f32x4;
typedef __attribute__((ext_vector_type(2))) unsigned int u32x2;

__device__ __forceinline__ unsigned short f2b(float f) {
    unsigned u = __float_as_uint(f);
    u += 0x7FFF + ((u >> 16) & 1);          // RNE
    return (unsigned short)(u >> 16);
}
__device__ __forceinline__ float b2f(unsigned short h) {
    return __uint_as_float((unsigned)h << 16);
}

// ---------------- init: zero counts/stats, split W, convert node_attr ----------------

__global__ __launch_bounds__(256) void init_k(int* __restrict__ counts,
                                              double* __restrict__ gsum,
                                              double* __restrict__ gsumsq,
                                              const float* __restrict__ w0,
                                              const float* __restrict__ w1,
                                              const float* __restrict__ w2,
                                              unsigned short* __restrict__ whi,
                                              unsigned short* __restrict__ wlo,
                                              const float* __restrict__ xf,
                                              unsigned short* __restrict__ nabf) {
    int bid = blockIdx.x;
    if (bid < NCHUNK) {
        int i = bid * 256 + threadIdx.x;
        if (i < NN) counts[i] = 0;
        if (i < 3 * DIM) { gsum[i] = 0.0; gsumsq[i] = 0.0; }
    } else if (bid < NCHUNK + 48) {
        int i = (bid - NCHUNK) * 256 + threadIdx.x;   // [0, 3*4096)
        int which = i >> 12;
        int off = (i & 4095) * 4;
        const float* w = (which == 0) ? w0 : ((which == 1) ? w1 : w2);
        float4 v = *(const float4*)(w + off);
        ushort4 h = {f2b(v.x), f2b(v.y), f2b(v.z), f2b(v.w)};
        ushort4 l = {f2b(v.x - b2f(h.x)), f2b(v.y - b2f(h.y)),
                     f2b(v.z - b2f(h.z)), f2b(v.w - b2f(h.w))};
        *(ushort4*)(whi + (size_t)which * 16384 + off) = h;
        *(ushort4*)(wlo + (size_t)which * 16384 + off) = l;
    } else {
        int idx = (bid - NCHUNK - 48) * 256 + threadIdx.x;  // [0, NN*DIM/4)
        f32x4 v = __builtin_nontemporal_load((const f32x4*)(xf + (size_t)idx * 4));
        u32x2 o;
        o[0] = (unsigned)f2b(v[0]) | ((unsigned)f2b(v[1]) << 16);
        o[1] = (unsigned)f2b(v[2]) | ((unsigned)f2b(v[3]) << 16);
        *(u32x2*)(nabf + (size_t)idx * 4) = o;   // reused by layer 1: keep cached
    }
}

// ---------------- CSR build ----------------

__global__ void count_k(const int* __restrict__ dst, int* __restrict__ counts, int E) {
    int i = blockIdx.x * 256 + threadIdx.x;
    if (i < E) atomicAdd(&counts[dst[i]], 1);
}

__global__ __launch_bounds__(256) void chunksum_k(const int* __restrict__ counts,
                                                  int* __restrict__ bsum) {
    __shared__ int lds[256];
    int i = blockIdx.x * 256 + threadIdx.x;
    lds[threadIdx.x] = (i < NN) ? counts[i] : 0;
    __syncthreads();
    for (int off = 128; off > 0; off >>= 1) {
        if (threadIdx.x < (unsigned)off) lds[threadIdx.x] += lds[threadIdx.x + off];
        __syncthreads();
    }
    if (threadIdx.x == 0) bsum[blockIdx.x] = lds[0];
}

__global__ __launch_bounds__(256) void chunkscan_k(const int* __restrict__ bsum,
                                                   int* __restrict__ bbase,
                                                   int* __restrict__ offsets) {
    __shared__ int lds[256];
    int t = threadIdx.x;
    int v = (t < NCHUNK) ? bsum[t] : 0;
    lds[t] = v;
    __syncthreads();
    for (int off = 1; off < 256; off <<= 1) {
        int a = (t >= (unsigned)off) ? lds[t - off] : 0;
        __syncthreads();
        lds[t] += a;
        __syncthreads();
    }
    if (t < NCHUNK) bbase[t] = lds[t] - v;
    if (t == 0) offsets[NN] = NE;
}

__global__ __launch_bounds__(256) void scatteroff_k(const int* __restrict__ counts,
                                                    const int* __restrict__ bbase,
                                                    int* __restrict__ offsets,
                                                    int* __restrict__ cursor) {
    __shared__ int lds[256];
    int t = threadIdx.x;
    int i = blockIdx.x * 256 + t;
    int v = (i < NN) ? counts[i] : 0;
    lds[t] = v;
    __syncthreads();
    for (int off = 1; off < 256; off <<= 1) {
        int a = (t >= (unsigned)off) ? lds[t - off] : 0;
        __syncthreads();
        lds[t] += a;
        __syncthreads();
    }
    if (i < NN) {
        int excl = bbase[blockIdx.x] + lds[t] - v;
        offsets[i] = excl;
        cursor[i] = excl;
    }
}

// index-only CSR fill (eattr conversion moved into layer 1)
__global__ void fill_k(const int* __restrict__ dst, const int* __restrict__ src,
                       int* __restrict__ cursor, int* __restrict__ csrc,
                       int* __restrict__ eidx, int E) {
    int i = blockIdx.x * 256 + threadIdx.x;
    if (i < E) {
        int p = atomicAdd(&cursor[dst[i]], 1);
        csrc[p] = src[i];
        eidx[p] = i;
    }
}

// ---------------- fused layer kernel ----------------
// Per block: 16 nodes. Phase A: 8 groups x 32 lanes aggregate (2 nodes each)
// into fp32 LDS. Phase B: bf16-A x split-bf16-W MFMA GEMM; per-layer BN stats
// via f64 atomics. BN of the previous layer folded on the fly (XMODE==1).
// XMODE: 1 = x bf16 + BN-fold from prev stats, 2 = x bf16 identity (layer 1).
// EMODE: 0 = read CSR-ordered bf16 ebf;
//        1 = read fp32 eattr via eidx (no ebf);
//        2 = read fp32 eattr via eidx (NT) AND write CSR-ordered bf16 ebf
//            (layer 1 producing the compressed edge stream for layers 2-3).
template <int XMODE, int EMODE>
__global__ __launch_bounds__(256) void layer_k(
        const unsigned short* __restrict__ xb,
        const double* __restrict__ gs_prev, const double* __restrict__ gq_prev,
        const float* __restrict__ gamma_prev, const float* __restrict__ beta_prev,
        const unsigned short* __restrict__ ebf, unsigned short* __restrict__ ebf_w,
        const float* __restrict__ eattr,
        const int* __restrict__ eidx, const int* __restrict__ offsets,
        const int* __restrict__ csrc,
        const unsigned short* __restrict__ whi, const unsigned short* __restrict__ wlo,
        const float* __restrict__ bias, unsigned short* __restrict__ yb,
        double* __restrict__ gs_cur, double* __restrict__ gq_cur) {
    __shared__ float sS[16][DIM + 4];        // stride 528B
    __shared__ unsigned short ylds[16][136];

    int tid = threadIdx.x;
    int lane31 = tid & 31;
    int grp = tid >> 5;
    int n0 = blockIdx.x * 16;
    int f = lane31 * 4;

    f32x4 sc, sh;
    if (XMODE == 1) {
#pragma unroll
        for (int j = 0; j < 4; ++j) {
            int d = f + j;
            double mean = gs_prev[d] * (1.0 / NN);
            double var = gq_prev[d] * (1.0 / NN) - mean * mean;
            float s = gamma_prev[d] * rsqrtf((float)var + BN_EPS);
            sc[j] = s;
            sh[j] = beta_prev[d] - (float)mean * s;
        }
    }

#pragma unroll
    for (int sub = 0; sub < 2; ++sub) {
        int n = n0 + grp * 2 + sub;
        float4 acc = make_float4(0.f, 0.f, 0.f, 0.f);
        int beg = offsets[n], end = offsets[n + 1];
        for (int b = beg; b < end; b += 32) {
            int kk = b + lane31;
            int s_l = (kk < end) ? csrc[kk] : 0;
            int e_l = 0;
            if (EMODE != 0) e_l = (kk < end) ? eidx[kk] : 0;
            int cnt = end - b;
            if (cnt > 32) cnt = 32;
#pragma unroll 4
            for (int t = 0; t < cnt; ++t) {
                int s = __shfl(s_l, t, 32);
                float4 ev;
                if (EMODE == 0) {
                    u32x2 ew = *(const u32x2*)(ebf + (size_t)(b + t) * DIM + f);
                    ev = make_float4(b2f((unsigned short)(ew[0] & 0xFFFFu)),
                                     b2f((unsigned short)(ew[0] >> 16)),
                                     b2f((unsigned short)(ew[1] & 0xFFFFu)),
                                     b2f((unsigned short)(ew[1] >> 16)));
                } else {
                    int e = __shfl(e_l, t, 32);
                    f32x4 v = __builtin_nontemporal_load(
                        (const f32x4*)(eattr + (size_t)e * DIM + f));
                    if (EMODE == 2) {
                        u32x2 o;
                        o[0] = (unsigned)f2b(v[0]) | ((unsigned)f2b(v[1]) << 16);
                        o[1] = (unsigned)f2b(v[2]) | ((unsigned)f2b(v[3]) << 16);
                        *(u32x2*)(ebf_w + (size_t)(b + t) * DIM + f) = o;
                    }
                    ev = make_float4(v[0], v[1], v[2], v[3]);
                }
                ushort4 u = *(const ushort4*)(xb + (size_t)s * DIM + f);
                float4 xv;
                if (XMODE == 1) {
                    xv = make_float4(fmaf(b2f(u.x), sc[0], sh[0]),
                                     fmaf(b2f(u.y), sc[1], sh[1]),
                                     fmaf(b2f(u.z), sc[2], sh[2]),
                                     fmaf(b2f(u.w), sc[3], sh[3]));
                } else {
                    xv = make_float4(b2f(u.x), b2f(u.y), b2f(u.z), b2f(u.w));
                }
                acc.x += fmaxf(xv.x + ev.x, 0.f);
                acc.y += fmaxf(xv.y + ev.y, 0.f);
                acc.z += fmaxf(xv.z + ev.z, 0.f);
                acc.w += fmaxf(xv.w + ev.w, 0.f);
            }
        }
        ushort4 u = *(const ushort4*)(xb + (size_t)n * DIM + f);
        float4 xn;
        if (XMODE == 1) {
            xn = make_float4(fmaf(b2f(u.x), sc[0], sh[0]), fmaf(b2f(u.y), sc[1], sh[1]),
                             fmaf(b2f(u.z), sc[2], sh[2]), fmaf(b2f(u.w), sc[3], sh[3]));
        } else {
            xn = make_float4(b2f(u.x), b2f(u.y), b2f(u.z), b2f(u.w));
        }
        float4 o = make_float4(xn.x + acc.x, xn.y + acc.y, xn.z + acc.z, xn.w + acc.w);
        *(float4*)(&sS[grp * 2 + sub][f]) = o;
    }
    __syncthreads();

    // ---- GEMM phase: A (bf16) x [Whi + Wlo] ----
    int wv = tid >> 6;
    int lane = tid & 63;
    int row = lane & 15;      // A row (node) / B col (dim)
    int kg = lane >> 4;       // k-group
    int d0 = wv * 32;
    const unsigned short* bh = whi + (size_t)(d0 + row) * DIM + kg * 8;
    const unsigned short* bl = wlo + (size_t)(d0 + row) * DIM + kg * 8;

    f32x4 acc0 = {0.f, 0.f, 0.f, 0.f};
    f32x4 acc1 = {0.f, 0.f, 0.f, 0.f};
#pragma unroll
    for (int ks = 0; ks < 4; ++ks) {
        const float* ap = &sS[row][kg * 8 + ks * 32];
        bf16x8 a;
#pragma unroll
        for (int j = 0; j < 8; ++j) a[j] = (short)f2b(ap[j]);
        bf16x8 b0h = *(const bf16x8*)(bh + ks * 32);
        bf16x8 b0l = *(const bf16x8*)(bl + ks * 32);
        bf16x8 b1h = *(const bf16x8*)(bh + 16 * DIM + ks * 32);
        bf16x8 b1l = *(const bf16x8*)(bl + 16 * DIM + ks * 32);
        acc0 = __builtin_amdgcn_mfma_f32_16x16x32_bf16(a, b0h, acc0, 0, 0, 0);
        acc0 = __builtin_amdgcn_mfma_f32_16x16x32_bf16(a, b0l, acc0, 0, 0, 0);
        acc1 = __builtin_amdgcn_mfma_f32_16x16x32_bf16(a, b1h, acc1, 0, 0, 0);
        acc1 = __builtin_amdgcn_mfma_f32_16x16x32_bf16(a, b1l, acc1, 0, 0, 0);
    }

    float bias0 = bias[d0 + row];
    float bias1 = bias[d0 + 16 + row];
    float s0 = 0.f, q0 = 0.f, s1 = 0.f, q1 = 0.f;
#pragma unroll
    for (int r = 0; r < 4; ++r) {
        int m = kg * 4 + r;
        float y0 = fmaxf(acc0[r] + bias0, 0.f);
        float y1 = fmaxf(acc1[r] + bias1, 0.f);
        ylds[m][d0 + row] = f2b(y0);
        ylds[m][d0 + 16 + row] = f2b(y1);
        s0 += y0; q0 += y0 * y0;
        s1 += y1; q1 += y1 * y1;
    }
    s0 += __shfl_xor(s0, 16); s0 += __shfl_xor(s0, 32);
    q0 += __shfl_xor(q0, 16); q0 += __shfl_xor(q0, 32);
    s1 += __shfl_xor(s1, 16); s1 += __shfl_xor(s1, 32);
    q1 += __shfl_xor(q1, 16); q1 += __shfl_xor(q1, 32);
    if (kg == 0) {
        atomicAdd(&gs_cur[d0 + row], (double)s0);
        atomicAdd(&gq_cur[d0 + row], (double)q0);
        atomicAdd(&gs_cur[d0 + 16 + row], (double)s1);
        atomicAdd(&gq_cur[d0 + 16 + row], (double)q1);
    }
    __syncthreads();
    int nrow = tid >> 4, seg = tid & 15;
    *(float4*)(yb + (size_t)(n0 + nrow) * DIM + seg * 8) =
        *(const float4*)(&ylds[nrow][seg * 8]);
}

// final BN applied from layer-3 stats, computed per-thread
__global__ __launch_bounds__(256) void norm_out_k(
        const unsigned short* __restrict__ yb,
        const double* __restrict__ gs, const double* __restrict__ gq,
        const float* __restrict__ gamma, const float* __restrict__ beta,
        float* __restrict__ out) {
    int i = blockIdx.x * 256 + threadIdx.x;   // [0, NN*DIM/4)
    int f = (i & 31) * 4;
    float sc[4], sh[4];
#pragma unroll
    for (int j = 0; j < 4; ++j) {
        int d = f + j;
        double mean = gs[d] * (1.0 / NN);
        double var = gq[d] * (1.0 / NN) - mean * mean;
        float s = gamma[d] * rsqrtf((float)var + BN_EPS);
        sc[j] = s;
        sh[j] = beta[d] - (float)mean * s;
    }
    ushort4 y = *(const ushort4*)(yb + (size_t)i * 4);
    float4 o;
    o.x = fmaf(b2f(y.x), sc[0], sh[0]);
    o.y = fmaf(b2f(y.y), sc[1], sh[1]);
    o.z = fmaf(b2f(y.z), sc[2], sh[2]);
    o.w = fmaf(b2f(y.w), sc[3], sh[3]);
    ((float4*)out)[i] = o;
}

// ---------------- launch ----------------

extern "C" void kernel_launch(void* const* d_in, const int* in_sizes, int n_in,
                              void* d_out, int out_size, void* d_ws, size_t ws_size,
                              hipStream_t stream) {
    const int* edge_index = (const int*)d_in[0];
    const int* srcs = edge_index;
    const int* dsts = edge_index + NE;
    const float* node_attr = (const float*)d_in[1];
    const float* eattr = (const float*)d_in[2];
    const float* Wp[3]    = {(const float*)d_in[3],  (const float*)d_in[7],  (const float*)d_in[11]};
    const float* bp[3]    = {(const float*)d_in[4],  (const float*)d_in[8],  (const float*)d_in[12]};
    const float* gammap[3]= {(const float*)d_in[5],  (const float*)d_in[9],  (const float*)d_in[13]};
    const float* betap[3] = {(const float*)d_in[6],  (const float*)d_in[10], (const float*)d_in[14]};

    size_t off = 0;
    char* base = (char*)d_ws;
    auto carve = [&](size_t bytes) -> void* {
        void* p = base + off;
        off += (bytes + 255) & ~(size_t)255;
        return p;
    };
    unsigned short* ybufA = (unsigned short*)carve((size_t)NN * DIM * 2);
    unsigned short* ybufB = (unsigned short*)carve((size_t)NN * DIM * 2);
    unsigned short* nabf = (unsigned short*)carve((size_t)NN * DIM * 2);
    int* csrc    = (int*)carve((size_t)NE * 4);
    int* eidx    = (int*)carve((size_t)NE * 4);
    int* offsets = (int*)carve((size_t)(NN + 1) * 4);
    int* cursor  = (int*)carve((size_t)NN * 4);
    int* bsum    = (int*)carve((size_t)NCHUNK * 4);
    int* bbase   = (int*)carve((size_t)NCHUNK * 4);
    int* counts  = (int*)carve((size_t)NN * 4);
    double* gsum = (double*)carve(3 * DIM * 8);    // per-layer stat sums
    double* gsumsq = (double*)carve(3 * DIM * 8);
    unsigned short* whi = (unsigned short*)carve(3 * DIM * DIM * 2);
    unsigned short* wlo = (unsigned short*)carve(3 * DIM * DIM * 2);
    int use_ebf = (off + (size_t)NE * DIM * 2 <= ws_size);
    unsigned short* ebf = use_ebf ? (unsigned short*)carve((size_t)NE * DIM * 2) : nullptr;

    init_k<<<NCHUNK + 48 + NABBLK, 256, 0, stream>>>(counts, gsum, gsumsq,
                                                     Wp[0], Wp[1], Wp[2], whi, wlo,
                                                     node_attr, nabf);
    count_k<<<(NE + 255) / 256, 256, 0, stream>>>(dsts, counts, NE);
    chunksum_k<<<NCHUNK, 256, 0, stream>>>(counts, bsum);
    chunkscan_k<<<1, 256, 0, stream>>>(bsum, bbase, offsets);
    scatteroff_k<<<NCHUNK, 256, 0, stream>>>(counts, bbase, offsets, cursor);
    fill_k<<<(NE + 255) / 256, 256, 0, stream>>>(dsts, srcs, cursor, csrc, eidx, NE);

    // ---- layer 1: nabf (identity) -> ybufA; reads eattr fp32, writes ebf ----
    if (use_ebf)
        layer_k<2, 2><<<NN / 16, 256, 0, stream>>>(nabf, nullptr, nullptr, nullptr, nullptr,
                                                   nullptr, ebf, eattr, eidx, offsets, csrc,
                                                   whi, wlo, bp[0], ybufA, gsum, gsumsq);
    else
        layer_k<2, 1><<<NN / 16, 256, 0, stream>>>(nabf, nullptr, nullptr, nullptr, nullptr,
                                                   nullptr, nullptr, eattr, eidx, offsets, csrc,
                                                   whi, wlo, bp[0], ybufA, gsum, gsumsq);

    // ---- layers 2,3: ping-pong A->B->A; BN of prev layer folded inline ----
    unsigned short* xin = ybufA;
    unsigned short* yout = ybufB;
    for (int l = 1; l < 3; ++l) {
        const double* gsp = gsum + (l - 1) * DIM;
        const double* gqp = gsumsq + (l - 1) * DIM;
        if (use_ebf)
            layer_k<1, 0><<<NN / 16, 256, 0, stream>>>(xin, gsp, gqp,
                                                       gammap[l - 1], betap[l - 1],
                                                       ebf, nullptr, eattr, eidx, offsets, csrc,
                                                       whi + l * DIM * DIM, wlo + l * DIM * DIM,
                                                       bp[l], yout,
                                                       gsum + l * DIM, gsumsq + l * DIM);
        else
            layer_k<1, 1><<<NN / 16, 256, 0, stream>>>(xin, gsp, gqp,
                                                       gammap[l - 1], betap[l - 1],
                                                       nullptr, nullptr, eattr, eidx, offsets, csrc,
                                                       whi + l * DIM * DIM, wlo + l * DIM * DIM,
                                                       bp[l], yout,
                                                       gsum + l * DIM, gsumsq + l * DIM);
        unsigned short* t = xin; xin = yout; yout = t;
    }
    norm_out_k<<<NN * DIM / 4 / 256, 256, 0, stream>>>(xin, gsum + 2 * DIM, gsumsq + 2 * DIM,
                                                       gammap[2], betap[2], (float*)d_out);
}